// Round 17
// baseline (67.869 us; speedup 1.0000x reference)
//
#include <hip/hip_runtime.h>
#include <math.h>

#define HH 1024
#define WW 2048
#define HW (HH*WW)
#define KC 32
#define NW 8192          /* total waves in kA grid (2048 blocks x 4 waves) */
#define CREGW 8          /* candidate slots per wave */
#define KCAP 12288       /* LDS-staged keys per median block */
#define NMED 128         /* median blocks */
#define SENT 0xFFFFFFFFu
#define BIAS 16777216.0f /* 2^24 */

typedef unsigned long long u64;

struct Scratch {
  unsigned hist0[2048];
  unsigned hist1[2048];
  unsigned hist2[2048];
  unsigned done0, doneA;
  int nvalid;
  float scale;
  float ck[KC], m2cy[KC], m2cx[KC];
  unsigned ccnt[NW];   // candidates per kA-wave
  unsigned cblk[NW];   // ground heights per kA-wave
};

__device__ __forceinline__ unsigned agent_load(const unsigned* p){
  return __hip_atomic_load(p, __ATOMIC_RELAXED, __HIP_MEMORY_SCOPE_AGENT);
}
__device__ __forceinline__ u64 agent_load64(const u64* p){
  return __hip_atomic_load(p, __ATOMIC_RELAXED, __HIP_MEMORY_SCOPE_AGENT);
}
__device__ __forceinline__ void agent_store64(u64* p, u64 v){
  __hip_atomic_store(p, v, __ATOMIC_RELAXED, __HIP_MEMORY_SCOPE_AGENT);
}

// ---- DPP 64-lane u64 max (VALU-speed, no LDS) ----
template<int CTRL>
__device__ __forceinline__ u64 dpp_mov64(u64 x){
  unsigned lo = (unsigned)x, hi = (unsigned)(x>>32);
  unsigned nlo = (unsigned)__builtin_amdgcn_update_dpp((int)lo, (int)lo, CTRL, 0xF, 0xF, false);
  unsigned nhi = (unsigned)__builtin_amdgcn_update_dpp((int)hi, (int)hi, CTRL, 0xF, 0xF, false);
  return ((u64)nhi<<32) | (u64)nlo;
}
__device__ __forceinline__ u64 wave_max64(u64 x){
  u64 y;
  y = dpp_mov64<0x111>(x); if (y > x) x = y;
  y = dpp_mov64<0x112>(x); if (y > x) x = y;
  y = dpp_mov64<0x114>(x); if (y > x) x = y;
  y = dpp_mov64<0x118>(x); if (y > x) x = y;
  y = dpp_mov64<0x142>(x); if (y > x) x = y;
  y = dpp_mov64<0x143>(x); if (y > x) x = y;
  unsigned mlo = (unsigned)__builtin_amdgcn_readlane((int)(unsigned)x, 63);
  unsigned mhi = (unsigned)__builtin_amdgcn_readlane((int)(unsigned)(x>>32), 63);
  return ((u64)mhi<<32) | (u64)mlo;
}

#define CSWAP(a,b) { if ((b) > (a)) { u64 _t=(a); (a)=(b); (b)=_t; } }

// grid barrier among NMED co-resident median blocks (per-BLOCK atomics only)
__device__ __forceinline__ void grid_bar(unsigned* ctr, unsigned target){
  __syncthreads();            // drains this block's vmem (hist atomics) first
  if (threadIdx.x == 0){
    atomicAdd(ctr, 1u);
    while (__hip_atomic_load(ctr, __ATOMIC_RELAXED, __HIP_MEMORY_SCOPE_AGENT) < target)
      __builtin_amdgcn_s_sleep(2);
  }
  __syncthreads();
}

// per-block redundant k-th-bucket pick over a global hist (512 threads, 4 bins/thread)
template<int PASS>
__device__ __forceinline__ void pick512(const unsigned* gh, unsigned* wsumL, unsigned* res){
  int t = threadIdx.x;
  unsigned v0 = agent_load(&gh[t*4+0]);
  unsigned v1 = agent_load(&gh[t*4+1]);
  unsigned v2 = agent_load(&gh[t*4+2]);
  unsigned v3 = agent_load(&gh[t*4+3]);
  int kin_prev = (PASS==0) ? 0 : (int)res[1];   // read BEFORE the sync below
  unsigned s = v0+v1+v2+v3;
  unsigned incl = s;
  #pragma unroll
  for (int d=1; d<64; d<<=1){ unsigned o = __shfl_up(incl, d); if ((t&63) >= d) incl += o; }
  unsigned excl = incl - s;
  if ((t&63)==63) wsumL[t>>6] = incl;
  __syncthreads();
  unsigned woff=0, total=0;
  #pragma unroll
  for (int w=0;w<8;w++){ unsigned xw=wsumL[w]; if (w < (t>>6)) woff += xw; total += xw; }
  unsigned pre = woff + excl;
  int k = (PASS==0) ? ((total>0) ? (int)((total-1)>>1) : 0) : kin_prev;
  if (total>0 && (unsigned)k >= pre && (unsigned)k < pre + s){
    unsigned kr = (unsigned)k - pre;
    int b_ = t*4;
    if (kr >= v0){ kr -= v0; b_++;
      if (kr >= v1){ kr -= v1; b_++;
        if (kr >= v2){ kr -= v2; b_++; } } }
    res[0] = (unsigned)b_; res[1] = kr;
  }
  if (t==0) res[2] = total;
  __syncthreads();
}

// streaming: candidate + ground compaction into PER-WAVE regions.
// 4 px/thread, grid 2048. ZERO barriers, ZERO LDS, ZERO atomics.
__global__ __launch_bounds__(256) void kA(const float* __restrict__ heat,
    const int* __restrict__ sem, const float* __restrict__ depth,
    const float* __restrict__ invK, u64* __restrict__ cand,
    unsigned* __restrict__ cheight, Scratch* __restrict__ sc){
  int t = threadIdx.x;
  if (blockIdx.x == 0){
    unsigned* hz = sc->hist0;          // hist0/1/2 contiguous
    for (int j=t; j<6144; j+=256) hz[j] = 0u;
    if (t==0){ sc->done0 = 0u; sc->doneA = 0u; }
  }
  int i4 = blockIdx.x*256 + t;
  int p = i4<<2;
  int y = p>>11, x = p&2047;
  int row = y<<11;
  int lane = t & 63;
  unsigned wid = (unsigned)(blockIdx.x*4 + (t>>6));

  float4 hq = ((const float4*)heat)[i4];
  int4   s4 = ((const int4*)sem)[i4];
  float4 dc = ((const float4*)depth)[i4];
  float  dl = depth[row + (x>0 ? x-1 : 0)];
  float  dr = depth[row + (x+4<WW ? x+4 : WW-1)];
  int rowu = (y>0)?    row-WW : row;
  int rowd = (y<HH-1)? row+WW : row;
  float4 du = ((const float4*)(depth + rowu))[x>>2];
  float4 dd = ((const float4*)(depth + rowd))[x>>2];
  float ik0=invK[0],ik1=invK[1],ik2=invK[2];
  float ik3=invK[3],ik4=invK[4],ik5=invK[5];
  float ik6=invK[6],ik7=invK[7],ik8=invK[8];

  float hv[4] = {hq.x,hq.y,hq.z,hq.w};
  int   sv[4] = {s4.x,s4.y,s4.z,s4.w};
  float dcv[4]= {dc.x,dc.y,dc.z,dc.w};
  float duv[4]= {du.x,du.y,du.z,du.w};
  float ddv[4]= {dd.x,dd.y,dd.z,dd.w};

  // per-wave exclusive scans (register-only cross-lane)
  unsigned npos = 0, ng = 0;
  #pragma unroll
  for (int j=0;j<4;j++){ npos += (hv[j] > 0.0f) ? 1u : 0u; ng += (sv[j]==0) ? 1u : 0u; }
  unsigned incc = npos, incg = ng;
  #pragma unroll
  for (int d=1; d<64; d<<=1){
    unsigned oc = __shfl_up(incc, d), og = __shfl_up(incg, d);
    if (lane >= d){ incc += oc; incg += og; }
  }

  float fy = (float)y;
  float a0=ik1*fy+ik2, a1=ik4*fy+ik5, a2=ik7*fy+ik8;
  float fyu=(y>0)?    fy-1.0f : fy;
  float fyd=(y<HH-1)? fy+1.0f : fy;
  float uu0=ik1*fyu+ik2, uu1=ik4*fyu+ik5, uu2=ik7*fyu+ik8;
  float ww0=ik1*fyd+ik2, ww1=ik4*fyd+ik5, ww2=ik7*fyd+ik8;
  float dxmv[4] = {dl, dcv[0], dcv[1], dcv[2]};
  float dxpv[4] = {dcv[1], dcv[2], dcv[3], dr};
  float h[4];
  #pragma unroll
  for (int j=0;j<4;j++){
    float fx  = (float)(x+j);
    float fxm = (x+j>0)?    fx-1.0f : fx;
    float fxp = (x+j<WW-1)? fx+1.0f : fx;
    float pc0=(ik0*fx +a0)*dcv[j],  pc1=(ik3*fx +a1)*dcv[j],  pc2=(ik6*fx +a2)*dcv[j];
    float pm0=(ik0*fxm+a0)*dxmv[j], pm1=(ik3*fxm+a1)*dxmv[j], pm2=(ik6*fxm+a2)*dxmv[j];
    float pp0=(ik0*fxp+a0)*dxpv[j], pp1=(ik3*fxp+a1)*dxpv[j], pp2=(ik6*fxp+a2)*dxpv[j];
    float pu0=(ik0*fx+uu0)*duv[j],  pu1=(ik3*fx+uu1)*duv[j],  pu2=(ik6*fx+uu2)*duv[j];
    float pd0=(ik0*fx+ww0)*ddv[j],  pd1=(ik3*fx+ww1)*ddv[j],  pd2=(ik6*fx+ww2)*ddv[j];
    float vx0=pp0-pm0, vx1=pp1-pm1, vx2=pp2-pm2;
    float vy0=pd0-pu0, vy1=pd1-pu1, vy2=pd2-pu2;
    float n0=vx1*vy2-vx2*vy1, n1=vx2*vy0-vx0*vy2, n2=vx0*vy1-vx1*vy0;
    float nn = sqrtf(n0*n0+n1*n1+n2*n2) + 1e-8f;
    h[j] = fabsf(pc0*n0+pc1*n1+pc2*n2) / nn;
  }

  // candidate writes (per-wave region of CREGW)
  if (npos){
    unsigned cslot = incc - npos;
    u64* cb = cand + ((size_t)wid * CREGW);
    #pragma unroll
    for (int j=0;j<4;j++){
      if (hv[j] > 0.0f){
        if (cslot < CREGW)
          cb[cslot] = ((u64)__float_as_uint(hv[j])<<32) | (u64)(unsigned)(~(unsigned)(p+j));
        cslot++;
      }
    }
  }
  // ground writes (per-wave region of 256)
  if (ng){
    unsigned gslot = (wid<<8) + (incg - ng);
    #pragma unroll
    for (int j=0;j<4;j++){
      if (sv[j]==0){ cheight[gslot++] = __float_as_uint(h[j]); }
    }
  }
  if (lane == 63){
    sc->ccnt[wid] = (incc > CREGW) ? CREGW : incc;
    sc->cblk[wid] = incg;
  }
}

// fused: blocks 0..255 = tournament stage A (+ticketed stage-B merge by last);
//        blocks 256..383 = LDS-staged 3-pass radix median with grid barriers
__global__ __launch_bounds__(512) void k_ms(const unsigned* __restrict__ ch,
    const u64* __restrict__ cand, u64* __restrict__ tour,
    Scratch* __restrict__ sc, const float* __restrict__ rch){
  __shared__ unsigned keys[KCAP];      // 48 KB
  __shared__ unsigned hsh[2048];
  __shared__ unsigned cnts[64], rstart[64];
  __shared__ unsigned wsumL[8];
  __shared__ unsigned res[3];          // {bucket, kRemain, total}
  __shared__ unsigned misc[2];         // {total, staged length}
  __shared__ u64 mls[4*KC];
  __shared__ int lastA;
  int t = threadIdx.x;
  int b = blockIdx.x;
  int lane = t & 63;
  int w = t >> 6;

  if (b < 256){
    // ---------- tournament stage A (wave 0 only) ----------
    if (t < 64){
      int r0 = b*32;
      // counts live in cnts[0..31]
      if (lane < 32) cnts[lane] = sc->ccnt[r0+lane];
      int s0 = lane*4;
      unsigned c0c = __shfl(cnts[0], 0); (void)c0c; // no-op, keep cnts in LDS
      u64 t0=0,t1=0,t2=0,t3=0;
      // need cnts visible to whole wave: wave-synchronous, LDS write then read ok
      t0 = ((s0&7)     < cnts[s0>>3])     ? cand[(size_t)r0*CREGW + s0]   : 0ULL;
      t1 = (((s0+1)&7) < cnts[(s0+1)>>3]) ? cand[(size_t)r0*CREGW + s0+1] : 0ULL;
      t2 = (((s0+2)&7) < cnts[(s0+2)>>3]) ? cand[(size_t)r0*CREGW + s0+2] : 0ULL;
      t3 = (((s0+3)&7) < cnts[(s0+3)>>3]) ? cand[(size_t)r0*CREGW + s0+3] : 0ULL;
      if (__ballot((t0|t1|t2|t3) != 0ULL) == 0ULL){
        if (lane < 32) agent_store64(&tour[b*32 + lane], 0ULL);
      } else {
        CSWAP(t0,t1) CSWAP(t2,t3) CSWAP(t0,t2) CSWAP(t1,t3) CSWAP(t1,t2)
        for (int r=0;r<32;r++){
          u64 m = wave_max64(t0);
          if (lane==0) agent_store64(&tour[b*32+r], m);
          if (m && t0==m){ t0=t1; t1=t2; t2=t3; t3=0ULL; }
        }
      }
    }
    __syncthreads();   // drains wave 0's agent stores (vmcnt) before ticket
    if (t==0) lastA = (atomicAdd(&sc->doneA, 1u) == 255u) ? 1 : 0;
    __syncthreads();
    if (lastA){
      // ---------- tournament stage B: merge 256 sorted-32 lists ----------
      const u64* lp = tour + (size_t)(w*64+lane)*KC;
      if (w < 4){
        u64 h0=agent_load64(&lp[0]), h1=agent_load64(&lp[1]);
        u64 h2=agent_load64(&lp[2]), h3=agent_load64(&lp[3]);
        int pp = 0;
        for (int r=0;r<KC;r++){
          u64 m = wave_max64(h0);
          if (lane==0) mls[w*KC+r] = m;
          if (m && h0==m){ pp++; h0=h1; h1=h2; h2=h3; h3 = (pp+3<KC)? agent_load64(&lp[pp+3]) : 0ULL; }
        }
      }
      __syncthreads();
      if (w == 0){
        u64 key = (lane<4) ? mls[lane*KC] : 0ULL;
        int p2=0, kk=0;
        for (int r=0;r<KC;r++){
          u64 m = wave_max64(key);
          if (m){
            if (lane==0){
              unsigned idx = ~(unsigned)(m & 0xFFFFFFFFULL);
              float cy = (float)(idx >> 11), cx = (float)(idx & 2047u);
              sc->ck[r]   = cy*cy + cx*cx + BIAS;
              sc->m2cy[r] = -2.0f*cy;
              sc->m2cx[r] = -2.0f*cx;
            }
            if (key==m){ p2++; key = (p2<KC)? mls[lane*KC+p2] : 0ULL; }
            kk = r+1;
          }
        }
        if (lane==0) sc->nvalid = kk;
      }
    }
    return;
  }

  // ---------- median blocks (mb in [0,128)): 64 wave-regions each ----------
  int mb = b - 256;
  int r0 = mb * 64;
  if (t==0){ res[0]=0u; res[1]=0u; res[2]=0u; misc[1]=0u; }
  __syncthreads();
  if (t < 64){
    unsigned c = sc->cblk[r0 + t];
    cnts[t] = c;
    unsigned inc = c;
    #pragma unroll
    for (int d=1; d<64; d<<=1){ unsigned o = __shfl_up(inc, d); if (lane >= d) inc += o; }
    rstart[t] = (inc <= KCAP) ? (inc - c) : SENT;
    if (inc <= KCAP) atomicMax(&misc[1], inc);
    if (t == 63) misc[0] = inc;
  }
  for (int j=t;j<2048;j+=512) hsh[j]=0u;
  __syncthreads();
  unsigned total = misc[0];
  bool anyov = (total > KCAP);
  unsigned nl = anyov ? misc[1] : total;

  // staging: wave-per-region (8 waves x 8 regions, regions <= 256)
  #pragma unroll
  for (int k=0;k<8;k++){
    int r = w + (k<<3);
    unsigned c = cnts[r], rs = rstart[r];
    if (rs != SENT){
      const unsigned* base = ch + ((size_t)(r0+r)<<8);
      for (unsigned i=lane; i<c; i+=64) keys[rs+i] = base[i];
    }
  }
  __syncthreads();

  // ---- pass 0 ----
  for (unsigned i=t; i<nl; i+=512) atomicAdd(&hsh[keys[i]>>21], 1u);
  if (anyov){
    for (int r=0;r<64;r++){
      if (rstart[r]==SENT){
        unsigned c = cnts[r];
        const unsigned* base = ch + ((size_t)(r0+r)<<8);
        for (unsigned i=t;i<c;i+=512) atomicAdd(&hsh[base[i]>>21], 1u);
      }
    }
  }
  __syncthreads();
  for (int j=t;j<2048;j+=512){ unsigned v=hsh[j]; if (v) atomicAdd(&sc->hist0[j], v); }
  grid_bar(&sc->done0, NMED);
  pick512<0>(sc->hist0, wsumL, res);
  unsigned tot0 = res[2];
  unsigned pref0 = res[0];
  for (int j=t;j<2048;j+=512) hsh[j]=0u;
  __syncthreads();

  // ---- pass 1 ----
  for (unsigned i=t; i<nl; i+=512){
    unsigned key = keys[i];
    if ((key>>21) == pref0) atomicAdd(&hsh[(key>>10)&2047u], 1u);
  }
  if (anyov){
    for (int r=0;r<64;r++){
      if (rstart[r]==SENT){
        unsigned c = cnts[r];
        const unsigned* base = ch + ((size_t)(r0+r)<<8);
        for (unsigned i=t;i<c;i+=512){ unsigned key=base[i]; if ((key>>21)==pref0) atomicAdd(&hsh[(key>>10)&2047u], 1u); }
      }
    }
  }
  __syncthreads();
  for (int j=t;j<2048;j+=512){ unsigned v=hsh[j]; if (v) atomicAdd(&sc->hist1[j], v); }
  grid_bar(&sc->done0, 2*NMED);
  pick512<1>(sc->hist1, wsumL, res);
  unsigned pref01 = (pref0 << 11) | res[0];
  for (int j=t;j<2048;j+=512) hsh[j]=0u;
  __syncthreads();

  // ---- pass 2 ----
  for (unsigned i=t; i<nl; i+=512){
    unsigned key = keys[i];
    if ((key>>10) == pref01) atomicAdd(&hsh[key & 1023u], 1u);
  }
  if (anyov){
    for (int r=0;r<64;r++){
      if (rstart[r]==SENT){
        unsigned c = cnts[r];
        const unsigned* base = ch + ((size_t)(r0+r)<<8);
        for (unsigned i=t;i<c;i+=512){ unsigned key=base[i]; if ((key>>10)==pref01) atomicAdd(&hsh[key & 1023u], 1u); }
      }
    }
  }
  __syncthreads();
  for (int j=t;j<2048;j+=512){ unsigned v=hsh[j]; if (v) atomicAdd(&sc->hist2[j], v); }
  grid_bar(&sc->done0, 3*NMED);
  pick512<2>(sc->hist2, wsumL, res);
  if (mb == 0 && t == 0){
    unsigned key = (pref01 << 10) | res[0];
    sc->scale = (tot0 > 0) ? (rch[0] / __uint_as_float(key)) : 0.0f;
  }
}

// labels + scaled depth + cam_out; 4 px/thread, grid 2048
__global__ __launch_bounds__(256) void k_final(const int* __restrict__ sem,
    const float* __restrict__ off, const float* __restrict__ depth,
    const float* __restrict__ invK, const Scratch* __restrict__ sc,
    float* __restrict__ out){
  __shared__ float sck[KC], smy[KC], smx[KC];
  __shared__ int snv; __shared__ float ssc;
  int t = threadIdx.x;
  if (t < KC){ sck[t]=sc->ck[t]; smy[t]=sc->m2cy[t]; smx[t]=sc->m2cx[t]; }
  if (t == 0){ snv = sc->nvalid; ssc = sc->scale; }
  __syncthreads();

  int i4 = blockIdx.x*256 + t;
  int p = i4<<2;
  int y = p>>11, x = p&2047;
  int4   s4 = ((const int4*)sem)[i4];
  float4 oy = ((const float4*)off)[i4];
  float4 ox = ((const float4*)(off+HW))[i4];
  float4 dc = ((const float4*)depth)[i4];

  float ik0=invK[0],ik1=invK[1],ik2=invK[2];
  float ik3=invK[3],ik4=invK[4],ik5=invK[5];
  float ik6=invK[6],ik7=invK[7],ik8=invK[8];
  float fy = (float)y;
  float a0=ik1*fy+ik2, a1=ik4*fy+ik5, a2=ik7*fy+ik8;
  int nv = snv; float s = ssc;

  int   sv[4]  = {s4.x,s4.y,s4.z,s4.w};
  float oyv[4] = {oy.x,oy.y,oy.z,oy.w};
  float oxv[4] = {ox.x,ox.y,ox.z,ox.w};
  float dv[4]  = {dc.x,dc.y,dc.z,dc.w};

  float ys[4], xs[4]; unsigned ub[4];
  #pragma unroll
  for (int j=0;j<4;j++){
    ys[j] = fy + oyv[j]; xs[j] = (float)(x+j) + oxv[j]; ub[j] = SENT;
  }
  for (int k=0;k<nv;k++){
    float ckk=sck[k], my=smy[k], mx=smx[k];
    #pragma unroll
    for (int j=0;j<4;j++){
      float tt = fmaf(ys[j], my, ckk);
      tt = fmaf(xs[j], mx, tt);
      unsigned uu = (__float_as_uint(tt) & ~31u) | (unsigned)k;
      ub[j] = uu < ub[j] ? uu : ub[j];
    }
  }
  float lab[4], depo[4];
  float4* cam = (float4*)(out + (size_t)2*HW);
  #pragma unroll
  for (int j=0;j<4;j++){
    int sj = sv[j];
    lab[j] = (sj >= 11 && nv > 0) ? (float)(sj*1000 + (int)(ub[j]&31u) + 1) : (float)sj;
    float fx = (float)(x+j);
    float ds = dv[j]*s;
    float p0=(ik0*fx+a0)*ds, p1=(ik3*fx+a1)*ds, p2=(ik6*fx+a2)*ds;
    bool filt = (lab[j]==10.0f) || (lab[j]==19.0f);
    depo[j] = filt ? 0.0f : ds;
    cam[p+j] = make_float4(p0, p1, p2, lab[j]);
  }
  ((float4*)out)[i4]      = make_float4(lab[0], lab[1], lab[2], lab[3]);
  ((float4*)(out+HW))[i4] = make_float4(depo[0], depo[1], depo[2], depo[3]);
}

extern "C" void kernel_launch(void* const* d_in, const int* in_sizes, int n_in,
                              void* d_out, int out_size, void* d_ws, size_t ws_size,
                              hipStream_t stream){
  const int*   sem   = (const int*)d_in[0];
  const float* heat  = (const float*)d_in[1];
  const float* off   = (const float*)d_in[2];
  const float* depth = (const float*)d_in[3];
  const float* invK  = (const float*)d_in[4];
  const float* rch   = (const float*)d_in[5];
  float* out = (float*)d_out;

  unsigned* cheight = (unsigned*)d_ws;                                       // NW*256*4 = 8MB
  u64* cand = (u64*)((char*)d_ws + (size_t)NW*256*4);                        // NW*CREGW*8 = 512KB
  u64* tour = (u64*)((char*)d_ws + (size_t)NW*256*4 + (size_t)NW*CREGW*8);   // 256*32*8 = 64KB
  Scratch* sc = (Scratch*)((char*)d_ws + (size_t)NW*256*4 + (size_t)NW*CREGW*8 + (size_t)256*KC*8);

  const int grid4 = HW/4/256;   // 2048

  kA<<<grid4, 256, 0, stream>>>(heat, sem, depth, invK, cand, cheight, sc);
  k_ms<<<256+NMED, 512, 0, stream>>>(cheight, cand, tour, sc, rch);
  k_final<<<grid4, 256, 0, stream>>>(sem, off, depth, invK, sc, out);
}

// Round 18
// 59.381 us; speedup vs baseline: 1.1429x; 1.1429x over previous
//
#include <hip/hip_runtime.h>
#include <math.h>

#define HH 1024
#define WW 2048
#define HW (HH*WW)
#define KC 32
#define NW 8192          /* total waves in kA grid (2048 blocks x 4 waves) */
#define CREGW 8          /* candidate slots per wave */
#define KCAP 12288       /* LDS-staged keys per median block */
#define NMED 128         /* median blocks (was 64 in R16) */
#define SENT 0xFFFFFFFFu
#define BIAS 16777216.0f /* 2^24 */

typedef unsigned long long u64;

struct Scratch {
  unsigned hist0[2048];
  unsigned hist1[2048];
  unsigned hist2[2048];
  unsigned done0;
  int nvalid;
  float scale;
  float ck[KC], m2cy[KC], m2cx[KC];
  unsigned ccnt[NW];   // candidates per kA-wave
  unsigned cblk[NW];   // ground heights per kA-wave
};

__device__ __forceinline__ unsigned agent_load(const unsigned* p){
  return __hip_atomic_load(p, __ATOMIC_RELAXED, __HIP_MEMORY_SCOPE_AGENT);
}

// ---- DPP 64-lane u64 max (VALU-speed, no LDS) ----
template<int CTRL>
__device__ __forceinline__ u64 dpp_mov64(u64 x){
  unsigned lo = (unsigned)x, hi = (unsigned)(x>>32);
  unsigned nlo = (unsigned)__builtin_amdgcn_update_dpp((int)lo, (int)lo, CTRL, 0xF, 0xF, false);
  unsigned nhi = (unsigned)__builtin_amdgcn_update_dpp((int)hi, (int)hi, CTRL, 0xF, 0xF, false);
  return ((u64)nhi<<32) | (u64)nlo;
}
__device__ __forceinline__ u64 wave_max64(u64 x){
  u64 y;
  y = dpp_mov64<0x111>(x); if (y > x) x = y;
  y = dpp_mov64<0x112>(x); if (y > x) x = y;
  y = dpp_mov64<0x114>(x); if (y > x) x = y;
  y = dpp_mov64<0x118>(x); if (y > x) x = y;
  y = dpp_mov64<0x142>(x); if (y > x) x = y;
  y = dpp_mov64<0x143>(x); if (y > x) x = y;
  unsigned mlo = (unsigned)__builtin_amdgcn_readlane((int)(unsigned)x, 63);
  unsigned mhi = (unsigned)__builtin_amdgcn_readlane((int)(unsigned)(x>>32), 63);
  return ((u64)mhi<<32) | (u64)mlo;
}

#define CSWAP(a,b) { if ((b) > (a)) { u64 _t=(a); (a)=(b); (b)=_t; } }

// grid barrier among NMED co-resident median blocks (per-BLOCK atomics only)
__device__ __forceinline__ void grid_bar(unsigned* ctr, unsigned target){
  __syncthreads();            // drains this block's vmem (hist atomics) first
  if (threadIdx.x == 0){
    atomicAdd(ctr, 1u);
    while (__hip_atomic_load(ctr, __ATOMIC_RELAXED, __HIP_MEMORY_SCOPE_AGENT) < target)
      __builtin_amdgcn_s_sleep(2);
  }
  __syncthreads();
}

// per-block redundant k-th-bucket pick over a global hist (512 threads, 4 bins/thread)
template<int PASS>
__device__ __forceinline__ void pick512(const unsigned* gh, unsigned* wsumL, unsigned* res){
  int t = threadIdx.x;
  unsigned v0 = agent_load(&gh[t*4+0]);
  unsigned v1 = agent_load(&gh[t*4+1]);
  unsigned v2 = agent_load(&gh[t*4+2]);
  unsigned v3 = agent_load(&gh[t*4+3]);
  int kin_prev = (PASS==0) ? 0 : (int)res[1];   // read BEFORE the sync below
  unsigned s = v0+v1+v2+v3;
  unsigned incl = s;
  #pragma unroll
  for (int d=1; d<64; d<<=1){ unsigned o = __shfl_up(incl, d); if ((t&63) >= d) incl += o; }
  unsigned excl = incl - s;
  if ((t&63)==63) wsumL[t>>6] = incl;
  __syncthreads();
  unsigned woff=0, total=0;
  #pragma unroll
  for (int w=0;w<8;w++){ unsigned xw=wsumL[w]; if (w < (t>>6)) woff += xw; total += xw; }
  unsigned pre = woff + excl;
  int k = (PASS==0) ? ((total>0) ? (int)((total-1)>>1) : 0) : kin_prev;
  if (total>0 && (unsigned)k >= pre && (unsigned)k < pre + s){
    unsigned kr = (unsigned)k - pre;
    int b_ = t*4;
    if (kr >= v0){ kr -= v0; b_++;
      if (kr >= v1){ kr -= v1; b_++;
        if (kr >= v2){ kr -= v2; b_++; } } }
    res[0] = (unsigned)b_; res[1] = kr;
  }
  if (t==0) res[2] = total;
  __syncthreads();
}

// streaming: candidate + ground compaction into PER-WAVE regions.
// 4 px/thread, grid 2048. ZERO barriers, ZERO LDS, ZERO atomics.
__global__ __launch_bounds__(256) void kA(const float* __restrict__ heat,
    const int* __restrict__ sem, const float* __restrict__ depth,
    const float* __restrict__ invK, u64* __restrict__ cand,
    unsigned* __restrict__ cheight, Scratch* __restrict__ sc){
  int t = threadIdx.x;
  if (blockIdx.x == 0){
    unsigned* hz = sc->hist0;          // hist0/1/2 contiguous
    for (int j=t; j<6144; j+=256) hz[j] = 0u;
    if (t==0) sc->done0 = 0u;
  }
  int i4 = blockIdx.x*256 + t;
  int p = i4<<2;
  int y = p>>11, x = p&2047;
  int row = y<<11;
  int lane = t & 63;
  unsigned wid = (unsigned)(blockIdx.x*4 + (t>>6));

  float4 hq = ((const float4*)heat)[i4];
  int4   s4 = ((const int4*)sem)[i4];
  float4 dc = ((const float4*)depth)[i4];
  float  dl = depth[row + (x>0 ? x-1 : 0)];
  float  dr = depth[row + (x+4<WW ? x+4 : WW-1)];
  int rowu = (y>0)?    row-WW : row;
  int rowd = (y<HH-1)? row+WW : row;
  float4 du = ((const float4*)(depth + rowu))[x>>2];
  float4 dd = ((const float4*)(depth + rowd))[x>>2];
  float ik0=invK[0],ik1=invK[1],ik2=invK[2];
  float ik3=invK[3],ik4=invK[4],ik5=invK[5];
  float ik6=invK[6],ik7=invK[7],ik8=invK[8];

  float hv[4] = {hq.x,hq.y,hq.z,hq.w};
  int   sv[4] = {s4.x,s4.y,s4.z,s4.w};
  float dcv[4]= {dc.x,dc.y,dc.z,dc.w};
  float duv[4]= {du.x,du.y,du.z,du.w};
  float ddv[4]= {dd.x,dd.y,dd.z,dd.w};

  // per-wave exclusive scans (register-only cross-lane)
  unsigned npos = 0, ng = 0;
  #pragma unroll
  for (int j=0;j<4;j++){ npos += (hv[j] > 0.0f) ? 1u : 0u; ng += (sv[j]==0) ? 1u : 0u; }
  unsigned incc = npos, incg = ng;
  #pragma unroll
  for (int d=1; d<64; d<<=1){
    unsigned oc = __shfl_up(incc, d), og = __shfl_up(incg, d);
    if (lane >= d){ incc += oc; incg += og; }
  }

  float fy = (float)y;
  float a0=ik1*fy+ik2, a1=ik4*fy+ik5, a2=ik7*fy+ik8;
  float fyu=(y>0)?    fy-1.0f : fy;
  float fyd=(y<HH-1)? fy+1.0f : fy;
  float uu0=ik1*fyu+ik2, uu1=ik4*fyu+ik5, uu2=ik7*fyu+ik8;
  float ww0=ik1*fyd+ik2, ww1=ik4*fyd+ik5, ww2=ik7*fyd+ik8;
  float dxmv[4] = {dl, dcv[0], dcv[1], dcv[2]};
  float dxpv[4] = {dcv[1], dcv[2], dcv[3], dr};
  float h[4];
  #pragma unroll
  for (int j=0;j<4;j++){
    float fx  = (float)(x+j);
    float fxm = (x+j>0)?    fx-1.0f : fx;
    float fxp = (x+j<WW-1)? fx+1.0f : fx;
    float pc0=(ik0*fx +a0)*dcv[j],  pc1=(ik3*fx +a1)*dcv[j],  pc2=(ik6*fx +a2)*dcv[j];
    float pm0=(ik0*fxm+a0)*dxmv[j], pm1=(ik3*fxm+a1)*dxmv[j], pm2=(ik6*fxm+a2)*dxmv[j];
    float pp0=(ik0*fxp+a0)*dxpv[j], pp1=(ik3*fxp+a1)*dxpv[j], pp2=(ik6*fxp+a2)*dxpv[j];
    float pu0=(ik0*fx+uu0)*duv[j],  pu1=(ik3*fx+uu1)*duv[j],  pu2=(ik6*fx+uu2)*duv[j];
    float pd0=(ik0*fx+ww0)*ddv[j],  pd1=(ik3*fx+ww1)*ddv[j],  pd2=(ik6*fx+ww2)*ddv[j];
    float vx0=pp0-pm0, vx1=pp1-pm1, vx2=pp2-pm2;
    float vy0=pd0-pu0, vy1=pd1-pu1, vy2=pd2-pu2;
    float n0=vx1*vy2-vx2*vy1, n1=vx2*vy0-vx0*vy2, n2=vx0*vy1-vx1*vy0;
    float nn = sqrtf(n0*n0+n1*n1+n2*n2) + 1e-8f;
    h[j] = fabsf(pc0*n0+pc1*n1+pc2*n2) / nn;
  }

  // candidate writes (per-wave region of CREGW)
  if (npos){
    unsigned cslot = incc - npos;
    u64* cb = cand + ((size_t)wid * CREGW);
    #pragma unroll
    for (int j=0;j<4;j++){
      if (hv[j] > 0.0f){
        if (cslot < CREGW)
          cb[cslot] = ((u64)__float_as_uint(hv[j])<<32) | (u64)(unsigned)(~(unsigned)(p+j));
        cslot++;
      }
    }
  }
  // ground writes (per-wave region of 256)
  if (ng){
    unsigned gslot = (wid<<8) + (incg - ng);
    #pragma unroll
    for (int j=0;j<4;j++){
      if (sv[j]==0){ cheight[gslot++] = __float_as_uint(h[j]); }
    }
  }
  if (lane == 63){
    sc->ccnt[wid] = (incc > CREGW) ? CREGW : incc;
    sc->cblk[wid] = incg;
  }
}

// tournament stage A: grid 256 x 1 wave; block b -> sorted top-32 of its 32 cand regions
__global__ __launch_bounds__(64) void k_top(const u64* __restrict__ cand,
    const Scratch* __restrict__ sc, u64* __restrict__ tour){
  __shared__ unsigned cnt32[32];
  int lane = threadIdx.x;
  int b = blockIdx.x, r0 = b*32;
  if (lane < 32) cnt32[lane] = sc->ccnt[r0+lane];
  __syncthreads();
  int s0 = lane*4;
  u64 t0 = ((s0&7)     < cnt32[s0>>3])     ? cand[(size_t)r0*CREGW + s0]   : 0ULL;
  u64 t1 = (((s0+1)&7) < cnt32[(s0+1)>>3]) ? cand[(size_t)r0*CREGW + s0+1] : 0ULL;
  u64 t2 = (((s0+2)&7) < cnt32[(s0+2)>>3]) ? cand[(size_t)r0*CREGW + s0+2] : 0ULL;
  u64 t3 = (((s0+3)&7) < cnt32[(s0+3)>>3]) ? cand[(size_t)r0*CREGW + s0+3] : 0ULL;
  // fast path: empty block -> write 32 zeros, done
  if (__ballot((t0|t1|t2|t3) != 0ULL) == 0ULL){
    if (lane < 32) tour[b*32 + lane] = 0ULL;
    return;
  }
  CSWAP(t0,t1) CSWAP(t2,t3) CSWAP(t0,t2) CSWAP(t1,t3) CSWAP(t1,t2)
  for (int r=0;r<32;r++){
    u64 m = wave_max64(t0);
    if (lane==0) tour[b*32+r] = m;
    if (m && t0==m){ t0=t1; t1=t2; t2=t3; t3=0ULL; }
  }
}

// fused median (blocks 0..NMED-1: LDS-staged 3-pass radix + grid barriers)
// + tournament merge (block NMED: 256 sorted lists -> centers)
__global__ __launch_bounds__(512) void k_med(const unsigned* __restrict__ ch,
    const u64* __restrict__ tour, Scratch* __restrict__ sc,
    const float* __restrict__ rch){
  __shared__ unsigned keys[KCAP];      // 48 KB
  __shared__ unsigned hsh[2048];
  __shared__ unsigned cnts[64], rstart[64];
  __shared__ unsigned wsumL[8];
  __shared__ unsigned res[3];          // {bucket, kRemain, total}
  __shared__ unsigned misc[2];         // {total, staged length}
  __shared__ u64 mls[4*KC];
  int t = threadIdx.x;
  int b = blockIdx.x;
  int lane = t & 63;
  int w = t >> 6;

  if (b == NMED){
    // ---------- tournament stage B ----------
    const u64* lp = tour + (size_t)(w*64+lane)*KC;
    if (w < 4){
      u64 h0=lp[0], h1=lp[1], h2=lp[2], h3=lp[3];
      int pp = 0;
      for (int r=0;r<KC;r++){
        u64 m = wave_max64(h0);
        if (lane==0) mls[w*KC+r] = m;
        if (m && h0==m){ pp++; h0=h1; h1=h2; h2=h3; h3 = (pp+3<KC)? lp[pp+3] : 0ULL; }
      }
    }
    __syncthreads();
    if (w == 0){
      u64 key = (lane<4) ? mls[lane*KC] : 0ULL;
      int p2=0, kk=0;
      for (int r=0;r<KC;r++){
        u64 m = wave_max64(key);
        if (m){
          if (lane==0){
            unsigned idx = ~(unsigned)(m & 0xFFFFFFFFULL);
            float cy = (float)(idx >> 11), cx = (float)(idx & 2047u);
            sc->ck[r]   = cy*cy + cx*cx + BIAS;
            sc->m2cy[r] = -2.0f*cy;
            sc->m2cx[r] = -2.0f*cx;
          }
          if (key==m){ p2++; key = (p2<KC)? mls[lane*KC+p2] : 0ULL; }
          kk = r+1;
        }
      }
      if (lane==0) sc->nvalid = kk;
    }
    return;
  }

  // ---------- median blocks 0..NMED-1: 64 wave-regions each ----------
  int r0 = b * 64;
  if (t==0){ res[0]=0u; res[1]=0u; res[2]=0u; misc[1]=0u; }
  __syncthreads();
  if (t < 64){
    unsigned c = sc->cblk[r0 + t];
    cnts[t] = c;
    unsigned inc = c;
    #pragma unroll
    for (int d=1; d<64; d<<=1){ unsigned o = __shfl_up(inc, d); if (lane >= d) inc += o; }
    rstart[t] = (inc <= KCAP) ? (inc - c) : SENT;
    if (inc <= KCAP) atomicMax(&misc[1], inc);
    if (t == 63) misc[0] = inc;
  }
  for (int j=t;j<2048;j+=512) hsh[j]=0u;
  __syncthreads();
  unsigned total = misc[0];
  bool anyov = (total > KCAP);
  unsigned nl = anyov ? misc[1] : total;

  // staging: wave-per-region (8 waves x 8 regions, regions <= 256)
  #pragma unroll
  for (int k=0;k<8;k++){
    int r = w + (k<<3);
    unsigned c = cnts[r], rs = rstart[r];
    if (rs != SENT){
      const unsigned* base = ch + ((size_t)(r0+r)<<8);
      for (unsigned i=lane; i<c; i+=64) keys[rs+i] = base[i];
    }
  }
  __syncthreads();

  // ---- pass 0 ----
  for (unsigned i=t; i<nl; i+=512) atomicAdd(&hsh[keys[i]>>21], 1u);
  if (anyov){
    for (int r=0;r<64;r++){
      if (rstart[r]==SENT){
        unsigned c = cnts[r];
        const unsigned* base = ch + ((size_t)(r0+r)<<8);
        for (unsigned i=t;i<c;i+=512) atomicAdd(&hsh[base[i]>>21], 1u);
      }
    }
  }
  __syncthreads();
  for (int j=t;j<2048;j+=512){ unsigned v=hsh[j]; if (v) atomicAdd(&sc->hist0[j], v); }
  grid_bar(&sc->done0, NMED);
  pick512<0>(sc->hist0, wsumL, res);
  unsigned tot0 = res[2];
  unsigned pref0 = res[0];
  for (int j=t;j<2048;j+=512) hsh[j]=0u;
  __syncthreads();

  // ---- pass 1 ----
  for (unsigned i=t; i<nl; i+=512){
    unsigned key = keys[i];
    if ((key>>21) == pref0) atomicAdd(&hsh[(key>>10)&2047u], 1u);
  }
  if (anyov){
    for (int r=0;r<64;r++){
      if (rstart[r]==SENT){
        unsigned c = cnts[r];
        const unsigned* base = ch + ((size_t)(r0+r)<<8);
        for (unsigned i=t;i<c;i+=512){ unsigned key=base[i]; if ((key>>21)==pref0) atomicAdd(&hsh[(key>>10)&2047u], 1u); }
      }
    }
  }
  __syncthreads();
  for (int j=t;j<2048;j+=512){ unsigned v=hsh[j]; if (v) atomicAdd(&sc->hist1[j], v); }
  grid_bar(&sc->done0, 2*NMED);
  pick512<1>(sc->hist1, wsumL, res);
  unsigned pref01 = (pref0 << 11) | res[0];
  for (int j=t;j<2048;j+=512) hsh[j]=0u;
  __syncthreads();

  // ---- pass 2 ----
  for (unsigned i=t; i<nl; i+=512){
    unsigned key = keys[i];
    if ((key>>10) == pref01) atomicAdd(&hsh[key & 1023u], 1u);
  }
  if (anyov){
    for (int r=0;r<64;r++){
      if (rstart[r]==SENT){
        unsigned c = cnts[r];
        const unsigned* base = ch + ((size_t)(r0+r)<<8);
        for (unsigned i=t;i<c;i+=512){ unsigned key=base[i]; if ((key>>10)==pref01) atomicAdd(&hsh[key & 1023u], 1u); }
      }
    }
  }
  __syncthreads();
  for (int j=t;j<2048;j+=512){ unsigned v=hsh[j]; if (v) atomicAdd(&sc->hist2[j], v); }
  grid_bar(&sc->done0, 3*NMED);
  pick512<2>(sc->hist2, wsumL, res);
  if (b == 0 && t == 0){
    unsigned key = (pref01 << 10) | res[0];
    sc->scale = (tot0 > 0) ? (rch[0] / __uint_as_float(key)) : 0.0f;
  }
}

// labels + scaled depth + cam_out; 4 px/thread, grid 2048
__global__ __launch_bounds__(256) void k_final(const int* __restrict__ sem,
    const float* __restrict__ off, const float* __restrict__ depth,
    const float* __restrict__ invK, const Scratch* __restrict__ sc,
    float* __restrict__ out){
  __shared__ float sck[KC], smy[KC], smx[KC];
  __shared__ int snv; __shared__ float ssc;
  int t = threadIdx.x;
  if (t < KC){ sck[t]=sc->ck[t]; smy[t]=sc->m2cy[t]; smx[t]=sc->m2cx[t]; }
  if (t == 0){ snv = sc->nvalid; ssc = sc->scale; }
  __syncthreads();

  int i4 = blockIdx.x*256 + t;
  int p = i4<<2;
  int y = p>>11, x = p&2047;
  int4   s4 = ((const int4*)sem)[i4];
  float4 oy = ((const float4*)off)[i4];
  float4 ox = ((const float4*)(off+HW))[i4];
  float4 dc = ((const float4*)depth)[i4];

  float ik0=invK[0],ik1=invK[1],ik2=invK[2];
  float ik3=invK[3],ik4=invK[4],ik5=invK[5];
  float ik6=invK[6],ik7=invK[7],ik8=invK[8];
  float fy = (float)y;
  float a0=ik1*fy+ik2, a1=ik4*fy+ik5, a2=ik7*fy+ik8;
  int nv = snv; float s = ssc;

  int   sv[4]  = {s4.x,s4.y,s4.z,s4.w};
  float oyv[4] = {oy.x,oy.y,oy.z,oy.w};
  float oxv[4] = {ox.x,ox.y,ox.z,ox.w};
  float dv[4]  = {dc.x,dc.y,dc.z,dc.w};

  float ys[4], xs[4]; unsigned ub[4];
  #pragma unroll
  for (int j=0;j<4;j++){
    ys[j] = fy + oyv[j]; xs[j] = (float)(x+j) + oxv[j]; ub[j] = SENT;
  }
  for (int k=0;k<nv;k++){
    float ckk=sck[k], my=smy[k], mx=smx[k];
    #pragma unroll
    for (int j=0;j<4;j++){
      float tt = fmaf(ys[j], my, ckk);
      tt = fmaf(xs[j], mx, tt);
      unsigned uu = (__float_as_uint(tt) & ~31u) | (unsigned)k;
      ub[j] = uu < ub[j] ? uu : ub[j];
    }
  }
  float lab[4], depo[4];
  float4* cam = (float4*)(out + (size_t)2*HW);
  #pragma unroll
  for (int j=0;j<4;j++){
    int sj = sv[j];
    lab[j] = (sj >= 11 && nv > 0) ? (float)(sj*1000 + (int)(ub[j]&31u) + 1) : (float)sj;
    float fx = (float)(x+j);
    float ds = dv[j]*s;
    float p0=(ik0*fx+a0)*ds, p1=(ik3*fx+a1)*ds, p2=(ik6*fx+a2)*ds;
    bool filt = (lab[j]==10.0f) || (lab[j]==19.0f);
    depo[j] = filt ? 0.0f : ds;
    cam[p+j] = make_float4(p0, p1, p2, lab[j]);
  }
  ((float4*)out)[i4]      = make_float4(lab[0], lab[1], lab[2], lab[3]);
  ((float4*)(out+HW))[i4] = make_float4(depo[0], depo[1], depo[2], depo[3]);
}

extern "C" void kernel_launch(void* const* d_in, const int* in_sizes, int n_in,
                              void* d_out, int out_size, void* d_ws, size_t ws_size,
                              hipStream_t stream){
  const int*   sem   = (const int*)d_in[0];
  const float* heat  = (const float*)d_in[1];
  const float* off   = (const float*)d_in[2];
  const float* depth = (const float*)d_in[3];
  const float* invK  = (const float*)d_in[4];
  const float* rch   = (const float*)d_in[5];
  float* out = (float*)d_out;

  unsigned* cheight = (unsigned*)d_ws;                                       // NW*256*4 = 8MB
  u64* cand = (u64*)((char*)d_ws + (size_t)NW*256*4);                        // NW*CREGW*8 = 512KB
  u64* tour = (u64*)((char*)d_ws + (size_t)NW*256*4 + (size_t)NW*CREGW*8);   // 256*32*8 = 64KB
  Scratch* sc = (Scratch*)((char*)d_ws + (size_t)NW*256*4 + (size_t)NW*CREGW*8 + (size_t)256*KC*8);

  const int grid4 = HW/4/256;   // 2048

  kA<<<grid4, 256, 0, stream>>>(heat, sem, depth, invK, cand, cheight, sc);
  k_top<<<256, 64, 0, stream>>>(cand, sc, tour);
  k_med<<<NMED+1, 512, 0, stream>>>(cheight, tour, sc, rch);
  k_final<<<grid4, 256, 0, stream>>>(sem, off, depth, invK, sc, out);
}